// Round 8
// baseline (311.644 us; speedup 1.0000x reference)
//
#include <hip/hip_runtime.h>
#include <hip/hip_bf16.h>
#include <math.h>

#define S1f 0.17677669529663687f  // 1/sqrt(32)

typedef float  f32x4 __attribute__((ext_vector_type(4)));
typedef short  s16x8 __attribute__((ext_vector_type(8)));

// ---------------- CG math (mirrors reference; runs per-block in phase 0) ----------------
struct cplx { double re, im; };
__device__ __forceinline__ cplx cmul(cplx a, cplx b){ return {a.re*b.re - a.im*b.im, a.re*b.im + a.im*b.re}; }
__device__ __forceinline__ double factd(int n){ double f=1.0; for(int i=2;i<=n;++i) f*=(double)i; return f; }

__device__ double su2cg(int j1,int j2,int j3,int m1,int m2){
  int m3 = m1+m2;
  if (m3 < -j3 || m3 > j3) return 0.0;
  double pref = sqrt((2.0*j3+1.0)*factd(j3+j1-j2)*factd(j3-j1+j2)*factd(j1+j2-j3)/factd(j1+j2+j3+1));
  pref *= sqrt(factd(j3+m3)*factd(j3-m3)*factd(j1-m1)*factd(j1+m1)*factd(j2-m2)*factd(j2+m2));
  double s = 0.0;
  for (int k=0;k<=j1+j2-j3;++k){
    int d1=j1+j2-j3-k, d2=j1-m1-k, d3=j2+m2-k, d4=j3-j2+m1+k, d5=j3-j1-m2+k;
    if (d1<0||d2<0||d3<0||d4<0||d5<0) continue;
    s += ((k&1)?-1.0:1.0)/(factd(k)*factd(d1)*factd(d2)*factd(d3)*factd(d4)*factd(d5));
  }
  return pref*s;
}

// real->complex SH change of basis, single entry q[r][c] for given l (incl (-i)^l phase)
__device__ __forceinline__ cplx q_entry(int l, int r, int c){
  const double rs2 = 0.70710678118654752440;
  double re=0.0, im=0.0;
  if (r < l){
    if (c == 2*l-r) re = rs2;
    if (c == r)     im = -rs2;
  } else if (r == l){
    if (c == l) re = 1.0;
  } else {
    double sg = ((r-l)&1)?-1.0:1.0;
    if (c == r)     re = sg*rs2;
    if (c == 2*l-r) im = sg*rs2;
  }
  cplx ph;
  if (l==0)      ph = {1.0, 0.0};
  else if (l==1) ph = {0.0,-1.0};
  else           ph = {-1.0,0.0};
  return cmul(ph, (cplx){re, im});
}

__device__ const int PL[15][3] = {
 {0,0,0},{0,1,1},{0,2,2},{1,0,1},{1,1,0},{1,1,1},{1,1,2},{1,2,1},{1,2,2},
 {2,0,2},{2,1,1},{2,1,2},{2,2,0},{2,2,1},{2,2,2}};

__device__ const int OFFL[3] = {0,32,128};

// ---------------- TP path: A-frag built in registers, B-frag from Wtp inline ----------------
// MFMA 16x16x32 bf16: A row=token(lane&15), A k=v=(lane>>4)*8+j; B col=w(lane&15), B k=v.
// C/D: col=lane&15 (w), row=(lane>>4)*4+reg (token).
template<int L1,int L2,int L3,int P,int S0>
__device__ __forceinline__ void tp_path(const float* __restrict__ y_s,
    const float* __restrict__ cg_lds, const float* __restrict__ Wtp,
    int lane, int wave, f32x4 (&acc)[5][2])
{
  constexpr int n1=2*L1+1, n2=2*L2+1, K=2*L3+1;
  constexpr int o1=(L1==0)?0:((L1==1)?32:128);
  constexpr int o2=(L2==0)?0:((L2==1)?32:128);
  const int t = lane&15, vg = lane>>4;
  const float* yt = y_s + t*289;
  float y2r[8][n2];
  #pragma unroll
  for (int vi=0;vi<8;++vi)
    #pragma unroll
    for (int j=0;j<n2;++j) y2r[vi][j] = yt[o2 + (vg*8+vi)*n2 + j];
  const float* cgp = cg_lds + P*128;

  #pragma unroll 1
  for (int uc=0;uc<4;++uc){
    const int u0 = wave*8 + uc*2;
    float y1r[2][n1];
    #pragma unroll
    for (int uu=0;uu<2;++uu)
      #pragma unroll
      for (int i=0;i<n1;++i) y1r[uu][i] = yt[o1 + (u0+uu)*n1 + i];
    // B-frags: bf16 of Wtp[p][u0+uu][v=vg*8+j][wt*16+t]
    s16x8 bfr[2][2];
    #pragma unroll
    for (int uu=0;uu<2;++uu)
      #pragma unroll
      for (int wt=0;wt<2;++wt){
        const float* wp = Wtp + (((P*32+u0+uu)*32 + vg*8)*32) + wt*16 + t;
        s16x8 b;
        #pragma unroll
        for (int j=0;j<8;++j){
          union { __hip_bfloat16 h; short s; } cv;
          cv.h = __float2bfloat16(wp[j*32]);
          b[j] = cv.s;
        }
        bfr[uu][wt] = b;
      }
    #pragma unroll
    for (int k=0;k<K;++k){
      float G[2][n2];
      #pragma unroll
      for (int uu=0;uu<2;++uu)
        #pragma unroll
        for (int j=0;j<n2;++j) G[uu][j]=0.f;
      #pragma unroll
      for (int i=0;i<n1;++i)
        #pragma unroll
        for (int j=0;j<n2;++j){
          float c = cgp[i*25 + j*5 + k];
          G[0][j] += y1r[0][i]*c;
          G[1][j] += y1r[1][i]*c;
        }
      #pragma unroll
      for (int uu=0;uu<2;++uu){
        s16x8 a;
        #pragma unroll
        for (int vi=0;vi<8;++vi){
          float af = 0.f;
          #pragma unroll
          for (int j=0;j<n2;++j) af += G[uu][j]*y2r[vi][j];
          union { __hip_bfloat16 h; short s; } cv;
          cv.h = __float2bfloat16(af);
          a[vi] = cv.s;
        }
        acc[S0+k][0] = __builtin_amdgcn_mfma_f32_16x16x32_bf16(a, bfr[uu][0], acc[S0+k][0],0,0,0);
        acc[S0+k][1] = __builtin_amdgcn_mfma_f32_16x16x32_bf16(a, bfr[uu][1], acc[S0+k][1],0,0,0);
      }
    }
  }
}

// lin2 for one l3 group; reads reduction rows [B..B+K), scalar stores (R5 form)
template<int L3,int B>
__device__ __forceinline__ void lin2_group(const float* __restrict__ S,
    const float* __restrict__ W2, int t, int sl, float* __restrict__ op)
{
  constexpr int K=2*L3+1;
  constexpr int o3=(L3==0)?0:((L3==1)?32:128);
  float z0[K], z1[K];
  #pragma unroll
  for (int k=0;k<K;++k){ z0[k]=0.f; z1[k]=0.f; }
  const float* w2p = W2 + L3*1024 + sl*2;
  #pragma unroll 4
  for (int w=0;w<32;++w){
    float2 wv = *(const float2*)(w2p + w*32);
    #pragma unroll
    for (int k=0;k<K;++k){
      float tb = S[(B+k)*528 + t*33 + w];
      z0[k] += tb*wv.x; z1[k] += tb*wv.y;
    }
  }
  #pragma unroll
  for (int k=0;k<K;++k){
    op[o3 + (sl*2)*K + k]   = z0[k]*S1f;
    op[o3 + (sl*2+1)*K + k] = z1[k]*S1f;
  }
}

// ---------------- single self-contained kernel, grid 1024 ----------------
// blocks [0,512): half 0 -> l3 in {0,1}, out cols [0,128)
// blocks [512,1024): half 1 -> l3=2, out cols [128,288)
// Phase 0 (all 15 CG paths) and phase 1 (lin1) are R5-verbatim in every block.
// LDS: y_s 18496B + smem 12288B + cg 7680B = 38464B. launch_bounds (256,2) as R5.
__global__ __launch_bounds__(256,2) void sheq_main(const float* __restrict__ x,
    const float* __restrict__ W1, const float* __restrict__ Wtp,
    const float* __restrict__ W2, float* __restrict__ out)
{
  __shared__ float y_s[16*289];                 // post-lin1 irreps
  __shared__ __align__(16) float smem[3072];    // phase0 fp64 (4w x 384 dbl) / lin1 staging (2576f) / red 5x528
  __shared__ float cg_lds[1920];                // CG, coeff folded: [p][i*25+j*5+k]

  int tid = threadIdx.x;
  int t = tid&15, sl = tid>>4;
  int lane = tid&63, wave = tid>>6;
  int half = blockIdx.x >> 9;
  int tok0 = (blockIdx.x & 511) * 16;
  const float* xb = x + (size_t)tok0*288;

  // ---- phase 0: build CG in LDS (R5 verbatim: all 15 paths) ----
  {
    double* dw  = ((double*)smem) + wave*384;
    double* Cp  = dw;
    double* TreP= dw + 128;
    double* TimP= dw + 256;
    #pragma unroll 1
    for (int c=0;c<4;++c){
      int p = c*4 + wave;
      bool act = (p < 15);
      int l1=0,l2=0,l3=0;
      if (act){ l1=PL[p][0]; l2=PL[p][1]; l3=PL[p][2]; }
      int n1=2*l1+1, n2=2*l2+1, n3=2*l3+1, tot=n1*n2*n3;
      if (act){
        for (int idx=lane; idx<tot; idx+=64){
          int i=idx/(n2*n3), r=idx-i*(n2*n3), k=r/n3, m=r-k*n3;
          Cp[idx] = ((i-l1)+(k-l2)==(m-l3)) ? su2cg(l1,l2,l3,i-l1,k-l2) : 0.0;
        }
      }
      __syncthreads();
      double pr=0.0, pim=0.0;
      if (act){
        for (int idx=lane; idx<tot; idx+=64){
          int j=idx/(n2*n3), r=idx-j*(n2*n3), L=r/n3, n=r-L*n3;
          double are=0.0, aim=0.0;
          for (int i=0;i<n1;++i) for (int k=0;k<n2;++k){
            int m=(i-l1)+(k-l2)+l3;
            if (m<0 || m>=n3) continue;
            double cv = Cp[(i*n2+k)*n3+m];
            if (cv==0.0) continue;
            cplx t1=q_entry(l1,i,j), t2=q_entry(l2,k,L), t3=q_entry(l3,m,n);
            t3.im = -t3.im;
            cplx tq = cmul(cmul(t1,t2),t3);
            are += tq.re*cv; aim += tq.im*cv;
          }
          TreP[idx]=are; TimP[idx]=aim;
          pr += are*are; pim += aim*aim;
        }
      }
      for (int off=1; off<64; off<<=1){ pr += __shfl_xor(pr,off); pim += __shfl_xor(pim,off); }
      __syncthreads();
      if (act){
        int useIm = (sqrt(pr) < 1e-6) ? 1 : 0;
        double norm = sqrt(useIm ? pim : pr);
        double co = (l3==0)? sqrt(1.0/3072.0) : ((l3==1)? sqrt(3.0/6144.0) : sqrt(5.0/6144.0));
        double scale = co/norm;
        for (int idx=lane; idx<128; idx+=64){
          float v=0.f;
          if (idx<125){
            int a=idx/25, r=idx-a*25, b=r/5, cc=r-b*5;
            if (a<n1 && b<n2 && cc<n3){
              int src=(a*n2+b)*n3+cc;
              double tv = useIm ? TimP[src] : TreP[src];
              v = (float)(tv*scale);
            }
          }
          cg_lds[p*128+idx]=v;
        }
      }
      __syncthreads();
    }
  }

  // ---- phase 1: lin1 (R5 verbatim) ----
  #pragma unroll
  for (int l=0;l<3;++l){
    const int nl=2*l+1, offl=OFFL[l], rl=32*nl;
    __syncthreads();
    for (int e=tid; e<16*rl; e+=256){
      int tt=e/rl, qq=e-tt*rl;
      smem[tt*161+qq]=xb[tt*288+offl+qq];
    }
    __syncthreads();
    float a0[5], a1[5];
    for (int i=0;i<nl;++i){ a0[i]=0.f; a1[i]=0.f; }
    const float* w1p = W1 + l*1024 + sl*2;
    const float* xr = smem + t*161;
    #pragma unroll 4
    for (int u=0;u<32;++u){
      float2 wv = *(const float2*)(w1p+u*32);
      for (int i=0;i<nl;++i){ float xv=xr[u*nl+i]; a0[i]+=xv*wv.x; a1[i]+=xv*wv.y; }
    }
    float* yp = y_s + t*289 + offl;
    for (int i=0;i<nl;++i){ yp[(sl*2)*nl+i]=a0[i]*S1f; yp[(sl*2+1)*nl+i]=a1[i]*S1f; }
  }
  __syncthreads();

  // ---- phase 2: TP via MFMA, barrier-free; this half's path subset only ----
  f32x4 acc[5][2];
  #pragma unroll
  for (int s=0;s<5;++s){ acc[s][0]=(f32x4){0.f,0.f,0.f,0.f}; acc[s][1]=(f32x4){0.f,0.f,0.f,0.f}; }

  if (half == 0){
    // R5 global order restricted to l3 in {0,1}: slots 0 (l3=0) and 1..3 (l3=1)
    tp_path<0,0,0, 0,0>(y_s,cg_lds,Wtp,lane,wave,acc);
    tp_path<0,1,1, 1,1>(y_s,cg_lds,Wtp,lane,wave,acc);
    tp_path<1,0,1, 3,1>(y_s,cg_lds,Wtp,lane,wave,acc);
    tp_path<1,1,0, 4,0>(y_s,cg_lds,Wtp,lane,wave,acc);
    tp_path<1,1,1, 5,1>(y_s,cg_lds,Wtp,lane,wave,acc);
    tp_path<1,2,1, 7,1>(y_s,cg_lds,Wtp,lane,wave,acc);
    tp_path<2,1,1,10,1>(y_s,cg_lds,Wtp,lane,wave,acc);
    tp_path<2,2,0,12,0>(y_s,cg_lds,Wtp,lane,wave,acc);
    tp_path<2,2,1,13,1>(y_s,cg_lds,Wtp,lane,wave,acc);
  } else {
    // l3=2 paths: slots 0..4
    tp_path<0,2,2, 2,0>(y_s,cg_lds,Wtp,lane,wave,acc);
    tp_path<1,1,2, 6,0>(y_s,cg_lds,Wtp,lane,wave,acc);
    tp_path<1,2,2, 8,0>(y_s,cg_lds,Wtp,lane,wave,acc);
    tp_path<2,0,2, 9,0>(y_s,cg_lds,Wtp,lane,wave,acc);
    tp_path<2,1,2,11,0>(y_s,cg_lds,Wtp,lane,wave,acc);
    tp_path<2,2,2,14,0>(y_s,cg_lds,Wtp,lane,wave,acc);
  }

  // ---- phase 3: cross-wave reduction into smem[s][t][w] (stride 33), 5 rows ----
  for (int wv=0;wv<4;++wv){
    if (wave==wv){
      #pragma unroll
      for (int s=0;s<5;++s)
        #pragma unroll
        for (int wt=0;wt<2;++wt)
          #pragma unroll
          for (int r=0;r<4;++r){
            int row = (lane>>4)*4 + r, col = wt*16 + (lane&15);
            float* pp = &smem[s*528 + row*33 + col];
            if (wv==0) *pp = acc[s][wt][r]; else *pp += acc[s][wt][r];
          }
    }
    __syncthreads();
  }

  // ---- lin2 (fp32 VALU), scalar stores (R5 form) ----
  float* op = out + (size_t)(tok0+t)*288;
  if (half == 0){
    lin2_group<0,0>(smem, W2, t, sl, op);
    lin2_group<1,1>(smem, W2, t, sl, op);
  } else {
    lin2_group<2,0>(smem, W2, t, sl, op);
  }
}

extern "C" void kernel_launch(void* const* d_in, const int* in_sizes, int n_in,
                              void* d_out, int out_size, void* d_ws, size_t ws_size,
                              hipStream_t stream) {
  const float* x   = (const float*)d_in[0];
  const float* W1  = (const float*)d_in[1];
  const float* Wtp = (const float*)d_in[2];
  const float* W2  = (const float*)d_in[3];
  float* out = (float*)d_out;

  sheq_main<<<dim3(1024), dim3(256), 0, stream>>>(x, W1, Wtp, W2, out);
}